// Round 2
// baseline (84.337 us; speedup 1.0000x reference)
//
#include <hip/hip_runtime.h>
#include <math.h>

#define NB 256
#define NV 2
#define NN 512
#define ND 10
#define NROWS (NB * NV * NN)   // rows per input array = 262144
#define THRESH_SQ 6.0f
#define EPS_W 1e-6f

// ---------------------------------------------------------------------------
// Prepack: n2[row] = sum of squares of vis dims (floats 5..8) for each row.
// Expression written identically to the main kernel / round-1 (fma-contracted
// the same way) so THRESH comparisons stay bit-identical.
// ---------------------------------------------------------------------------
__global__ __launch_bounds__(256)
void prepack_n2(const float* __restrict__ achieved,
                const float* __restrict__ desired,
                float* __restrict__ n2A,
                float* __restrict__ n2B)
{
    int r = blockIdx.x * 256 + threadIdx.x;   // 0 .. 2*NROWS-1
    const float* src;
    float* dst;
    int row;
    if (r < NROWS) { src = achieved; dst = n2A; row = r; }
    else           { src = desired;  dst = n2B; row = r - NROWS; }
    const float* p = src + (size_t)row * ND;
    float v0 = p[5], v1 = p[6], v2 = p[7], v3 = p[8];
    dst[row] = v0*v0 + v1*v1 + v2*v2 + v3*v3;
}

// ---------------------------------------------------------------------------
// One block per (bv, direction). 512 threads, each owns one query row.
// Sources are streamed through wave-uniform loads (scalar pipe), queries and
// the argmin state live in VGPRs. LDS only holds the count-scatter array and
// reduction scratch.
// dir 0: queries = desired (goals), sources = achieved (states)  -> r_g2s
// dir 1: queries = achieved,        sources = desired            -> r_s2g
// ---------------------------------------------------------------------------
template<bool N2PACKED>
__global__ __launch_bounds__(512, 8)
void chamfer_dir(const float* __restrict__ achieved,
                 const float* __restrict__ desired,
                 const float* __restrict__ n2A,
                 const float* __restrict__ n2B,
                 float* __restrict__ r_out)
{
    const int bvd = blockIdx.x;        // 0..1023
    const int bv  = bvd >> 1;
    const int dir = bvd & 1;
    const int tid = threadIdx.x;       // 0..511  (query index m)

    __shared__ int   cnt[NN];
    __shared__ float redf[8];
    __shared__ int   redi[8];

    const float* Qr = (dir == 0 ? desired  : achieved) + (size_t)bv * NN * ND;
    const float* Sv = (dir == 0 ? achieved : desired ) + (size_t)bv * NN * ND;
    const float* Sn = (dir == 0 ? n2A      : n2B     ) + (size_t)bv * NN;

    cnt[tid] = 0;

    // ---- own query (per-lane loads, one-time) ----
    const float* qp = Qr + (size_t)tid * ND;
    const float qx = qp[0], qy = qp[1];
    const float q0 = qp[5], q1 = qp[6], q2 = qp[7], q3 = qp[8];
    const float qn2 = q0*q0 + q1*q1 + q2*q2 + q3*q3;

    __syncthreads();

    // ---- argmin over sources: p = nn2 - 2*dot  (qn2 constant, folded out) ----
    float best = INFINITY;
    int   bi   = 0;
    #pragma unroll 8
    for (int n = 0; n < NN; ++n) {
        const float* rp = Sv + n * ND;       // wave-uniform address -> s_load
        float s0 = rp[5], s1 = rp[6], s2 = rp[7], s3 = rp[8];
        float nn2;
        if (N2PACKED) nn2 = Sn[n];           // wave-uniform -> s_load
        else          nn2 = s0*s0 + s1*s1 + s2*s2 + s3*s3;
        float d = fmaf(s0, q0, fmaf(s1, q1, fmaf(s2, q2, s3 * q3)));
        float p = fmaf(-2.0f, d, nn2);
        if (p < best) { best = p; bi = n; }
    }

    const float md  = best + qn2;
    const bool  lat = md > THRESH_SQ;

    if (!lat) atomicAdd(&cnt[bi], 1);
    __syncthreads();

    // ---- per-query contribution ----
    float sum = 0.0f;
    if (!lat) {
        const float* sp = Sv + (size_t)bi * ND;   // divergent gather (L1/L2 hot)
        float dx = qx - sp[0];
        float dy = qy - sp[1];
        float w  = 1.0f / ((float)cnt[bi] + EPS_W);
        sum = w * sqrtf(dx*dx + dy*dy);
    }
    int pk = ((cnt[tid] > 0) ? 1 : 0) | (lat ? 0x10000 : 0);

    // ---- block reduction: sum (f32), groups (low 16), latent count (high) ----
    #pragma unroll
    for (int off = 32; off > 0; off >>= 1) {
        sum += __shfl_down(sum, off);
        pk  += __shfl_down(pk, off);
    }
    const int lane = tid & 63, wid = tid >> 6;
    if (lane == 0) { redf[wid] = sum; redi[wid] = pk; }
    __syncthreads();
    if (tid == 0) {
        float s = 0.0f; int P = 0;
        #pragma unroll
        for (int i = 0; i < 8; ++i) { s += redf[i]; P += redi[i]; }
        int   grp    = P & 0xFFFF;
        float unm    = (P >> 16) ? 1.0f : 0.0f;
        float groups = fmaxf((float)grp + unm, 1.0f);
        r_out[bvd] = -(s + unm) / groups;
    }
}

// out[b] = mean_v( 0.5*(rA + rB) );  r index = b*4 + v*2 + dir
__global__ void chamfer_finalize(const float* __restrict__ r, float* __restrict__ out)
{
    int b = blockIdx.x * 256 + threadIdx.x;
    if (b < NB) {
        float rv0 = 0.5f * (r[4*b + 0] + r[4*b + 1]);
        float rv1 = 0.5f * (r[4*b + 2] + r[4*b + 3]);
        out[b] = 0.5f * (rv0 + rv1);
    }
}

extern "C" void kernel_launch(void* const* d_in, const int* in_sizes, int n_in,
                              void* d_out, int out_size, void* d_ws, size_t ws_size,
                              hipStream_t stream)
{
    const float* achieved = (const float*)d_in[0];
    const float* desired  = (const float*)d_in[1];
    float* out = (float*)d_out;

    const size_t n2_elems = (size_t)2 * NROWS;            // 524288 floats
    const size_t need     = n2_elems * 4 + NB * NV * 2 * 4;

    if (ws_size >= need) {
        float* n2A = (float*)d_ws;
        float* n2B = n2A + NROWS;
        float* r   = n2B + NROWS;
        prepack_n2<<<(2 * NROWS) / 256, 256, 0, stream>>>(achieved, desired, n2A, n2B);
        chamfer_dir<true><<<NB * NV * 2, 512, 0, stream>>>(achieved, desired, n2A, n2B, r);
        chamfer_finalize<<<1, 256, 0, stream>>>(r, out);
    } else {
        float* r = (float*)d_ws;                          // 4 KB
        chamfer_dir<false><<<NB * NV * 2, 512, 0, stream>>>(achieved, desired, nullptr, nullptr, r);
        chamfer_finalize<<<1, 256, 0, stream>>>(r, out);
    }
}

// Round 3
// 63.830 us; speedup vs baseline: 1.3213x; 1.3213x over previous
//
#include <hip/hip_runtime.h>
#include <math.h>

#define NB 256
#define NV 2
#define NN 512
#define ND 10
#define THRESH_SQ 6.0f
#define EPS_W 1e-6f

typedef __attribute__((ext_vector_type(8))) short bf16x8;
typedef __attribute__((ext_vector_type(4))) float f32x4;

__device__ __forceinline__ unsigned short f2bf(float x) {
    union { float f; unsigned u; } v; v.f = x;
    unsigned r = v.u + 0x7FFFu + ((v.u >> 16) & 1u);   // RNE
    return (unsigned short)(r >> 16);
}
__device__ __forceinline__ float bf2f(unsigned short h) {
    union { unsigned u; float f; } v; v.u = ((unsigned)h) << 16; return v.f;
}
__device__ __forceinline__ void split3(float x, unsigned short* s) {
    unsigned short h = f2bf(x); float r = x - bf2f(h);
    unsigned short m = f2bf(r); float r2 = r - bf2f(m);
    s[0] = h; s[1] = m; s[2] = f2bf(r2);
}

// chunk-major record layout, XOR-swizzled; byte offset within a 32KB region
__device__ __forceinline__ int recaddr(int c, int row) {
    return (c << 13) + ((row << 4) ^ (c << 5));
}

// One block (512 thr) per bv. P computed once via bf16-split MFMA; row- and
// col-argmin extracted from fragments; round-1 epilogue formulas.
__global__ __launch_bounds__(512)
void chamfer_bv(const float* __restrict__ achieved,
                const float* __restrict__ desired,
                float* __restrict__ rv_out)
{
    const int bv  = blockIdx.x;
    const int tid = threadIdx.x;

    __shared__ __align__(16) char lds[65536];
    // [0,32768)      : A records (achieved, -2-scaled splits + sn2 splits + 1s)
    //                  -> overlaid by colSlotV[512][8] (16K) + colSlotI (16K)
    // [32768,65536)  : B records (desired splits + 1s + gn2 splits)
    //                  -> overlaid by rowBestV/I, cntA, cntB, red arrays

    const float* arow = achieved + ((size_t)bv * NN + tid) * ND;
    const float* drow = desired  + ((size_t)bv * NN + tid) * ND;

    // ---------------- staging: build 32-slot bf16 records ----------------
    {
        unsigned short tA[32], tB[32];
        float a5 = arow[5], a6 = arow[6], a7 = arow[7], a8 = arow[8];
        float g5 = drow[5], g6 = drow[6], g7 = drow[7], g8 = drow[8];
        unsigned short us[4][3], gs[4][3];
        split3(-2.0f*a5, us[0]); split3(-2.0f*a6, us[1]);
        split3(-2.0f*a7, us[2]); split3(-2.0f*a8, us[3]);
        split3(g5, gs[0]); split3(g6, gs[1]); split3(g7, gs[2]); split3(g8, gs[3]);
        float sn2 = a5*a5 + a6*a6 + a7*a7 + a8*a8;
        float gn2 = g5*g5 + g6*g6 + g7*g7 + g8*g8;
        unsigned short sn[3], gn[3];
        split3(sn2, sn); split3(gn2, gn);
        // product pairs (i,j) with i+j<=2
        const int pi[6] = {0,0,1,2,1,0};
        const int pj[6] = {0,1,0,0,1,2};
        #pragma unroll
        for (int d = 0; d < 4; ++d) {
            #pragma unroll
            for (int p = 0; p < 6; ++p) {
                tA[d*6+p] = us[d][pi[p]];
                tB[d*6+p] = gs[d][pj[p]];
            }
        }
        const unsigned short ONE = 0x3F80;
        tA[24]=sn[0]; tA[25]=sn[1]; tA[26]=sn[2]; tA[27]=ONE; tA[28]=ONE; tA[29]=ONE;
        tB[24]=ONE;   tB[25]=ONE;   tB[26]=ONE;   tB[27]=gn[0]; tB[28]=gn[1]; tB[29]=gn[2];
        tA[30]=0; tA[31]=0; tB[30]=0; tB[31]=0;
        #pragma unroll
        for (int c = 0; c < 4; ++c) {
            bf16x8 va, vb;
            #pragma unroll
            for (int e = 0; e < 8; ++e) { va[e] = (short)tA[c*8+e]; vb[e] = (short)tB[c*8+e]; }
            *(bf16x8*)(lds + recaddr(c, tid))         = va;
            *(bf16x8*)(lds + 32768 + recaddr(c, tid)) = vb;
        }
    }
    __syncthreads();

    const int lane = tid & 63, wid = tid >> 6;
    const int lrow = lane & 15, lchk = lane >> 4;

    // A-frags for this wave's 64 rows (n = wid*64 + nt*16 + (lane&15))
    bf16x8 afr[4];
    #pragma unroll
    for (int nt = 0; nt < 4; ++nt)
        afr[nt] = *(const bf16x8*)(lds + recaddr(lchk, (wid<<6) + (nt<<4) + lrow));
    __syncthreads();   // A region dead -> colSlot writes allowed

    float* colSlotV = (float*)lds;              // [512][8]
    int*   colSlotI = (int*)(lds + 16384);      // [512][8]

    float rpV[4][4]; int rpI[4][4];
    #pragma unroll
    for (int nt = 0; nt < 4; ++nt)
        #pragma unroll
        for (int j = 0; j < 4; ++j) { rpV[nt][j] = INFINITY; rpI[nt][j] = 0; }

    const f32x4 z = {0.0f, 0.0f, 0.0f, 0.0f};

    // ---------------- main loop: 32 m-tiles x 4 n-tiles ----------------
    #pragma unroll 4
    for (int mt = 0; mt < 32; ++mt) {
        bf16x8 bfr = *(const bf16x8*)(lds + 32768 + recaddr(lchk, (mt<<4) + lrow));
        const int mcur = (mt<<4) + lrow;
        float cv = INFINITY; int ci = 0;
        #pragma unroll
        for (int nt = 0; nt < 4; ++nt) {
            f32x4 acc = __builtin_amdgcn_mfma_f32_16x16x32_bf16(afr[nt], bfr, z, 0, 0, 0);
            #pragma unroll
            for (int j = 0; j < 4; ++j) {
                float p = acc[j];
                int n = (wid<<6) + (nt<<4) + (lchk<<2) + j;
                if (p < rpV[nt][j]) { rpV[nt][j] = p; rpI[nt][j] = mcur; }  // row: min over m
                if (p < cv)         { cv = p; ci = n; }                      // col: min over n
            }
        }
        // combine col candidate across the 4 lchk groups (same m per lrow)
        #pragma unroll
        for (int s = 16; s <= 32; s <<= 1) {
            float pv = __shfl_xor(cv, s);
            int   qi = __shfl_xor(ci, s);
            if (pv < cv || (pv == cv && qi < ci)) { cv = pv; ci = qi; }
        }
        if (lane < 16) {
            colSlotV[mcur*8 + wid] = cv;
            colSlotI[mcur*8 + wid] = ci;
        }
    }
    __syncthreads();   // B region dead

    float* rowBestV = (float*)(lds + 32768);
    int*   rowBestI = (int*)(lds + 32768 + 2048);
    int*   cntA     = (int*)(lds + 32768 + 4096);
    int*   cntB     = (int*)(lds + 32768 + 6144);
    float* redF     = (float*)(lds + 32768 + 8192);        // [8][2]
    int*   redI2    = (int*)(lds + 32768 + 8192 + 64);     // [8][2]

    // row combine across the 16 lrow lanes (same n per lchk group)
    #pragma unroll
    for (int nt = 0; nt < 4; ++nt) {
        #pragma unroll
        for (int j = 0; j < 4; ++j) {
            float v = rpV[nt][j]; int i = rpI[nt][j];
            #pragma unroll
            for (int s = 1; s <= 8; s <<= 1) {
                float pv = __shfl_xor(v, s);
                int   qi = __shfl_xor(i, s);
                if (pv < v || (pv == v && qi < i)) { v = pv; i = qi; }
            }
            if (lrow == 0) {
                int n = (wid<<6) + (nt<<4) + (lchk<<2) + j;
                rowBestV[n] = v; rowBestI[n] = i;
            }
        }
    }
    cntA[tid] = 0; cntB[tid] = 0;
    __syncthreads();

    // final col combine: thread owns goal m = tid
    float mdA = INFINITY; int miA = 0;
    #pragma unroll
    for (int w = 0; w < 8; ++w) {
        float v = colSlotV[tid*8 + w];
        int   i = colSlotI[tid*8 + w];
        if (v < mdA || (v == mdA && i < miA)) { mdA = v; miA = i; }
    }
    float mdB = rowBestV[tid]; int miB = rowBestI[tid];   // state n = tid

    const bool latA = mdA > THRESH_SQ;
    const bool latB = mdB > THRESH_SQ;
    if (!latA) atomicAdd(&cntA[miA], 1);
    if (!latB) atomicAdd(&cntB[miB], 1);
    __syncthreads();

    float sumA = 0.0f, sumB = 0.0f;
    if (!latA) {
        const float* sp = achieved + ((size_t)bv * NN + miA) * ND;
        float dx = drow[0] - sp[0], dy = drow[1] - sp[1];
        float w = 1.0f / ((float)cntA[miA] + EPS_W);
        sumA = w * sqrtf(dx*dx + dy*dy);
    }
    if (!latB) {
        const float* gp = desired + ((size_t)bv * NN + miB) * ND;
        float dx = arow[0] - gp[0], dy = arow[1] - gp[1];
        float w = 1.0f / ((float)cntB[miB] + EPS_W);
        sumB = w * sqrtf(dx*dx + dy*dy);
    }
    int grpPk = ((cntA[tid] > 0) ? 1 : 0) | ((cntB[tid] > 0) ? (1 << 16) : 0);
    int latPk = (latA ? 1 : 0) | (latB ? 2 : 0);

    #pragma unroll
    for (int off = 32; off > 0; off >>= 1) {
        sumA  += __shfl_down(sumA, off);
        sumB  += __shfl_down(sumB, off);
        grpPk += __shfl_down(grpPk, off);
        latPk |= __shfl_down(latPk, off);
    }
    if (lane == 0) {
        redF[wid*2] = sumA; redF[wid*2+1] = sumB;
        redI2[wid*2] = grpPk; redI2[wid*2+1] = latPk;
    }
    __syncthreads();
    if (tid == 0) {
        float sA = 0.0f, sB = 0.0f; int G = 0, L = 0;
        #pragma unroll
        for (int w2 = 0; w2 < 8; ++w2) {
            sA += redF[w2*2]; sB += redF[w2*2+1];
            G  += redI2[w2*2]; L |= redI2[w2*2+1];
        }
        float unmA = (L & 1) ? 1.0f : 0.0f;
        float unmB = (L & 2) ? 1.0f : 0.0f;
        float gA = (float)(G & 0xFFFF), gB = (float)((unsigned)G >> 16);
        float rA = -(sA + unmA) / fmaxf(gA + unmA, 1.0f);
        float rB = -(sB + unmB) / fmaxf(gB + unmB, 1.0f);
        rv_out[bv] = 0.5f * (rA + rB);
    }
}

// out[b] = mean over v
__global__ void chamfer_finalize(const float* __restrict__ rv, float* __restrict__ out)
{
    int b = blockIdx.x * 256 + threadIdx.x;
    if (b < NB) out[b] = 0.5f * (rv[2*b] + rv[2*b + 1]);
}

extern "C" void kernel_launch(void* const* d_in, const int* in_sizes, int n_in,
                              void* d_out, int out_size, void* d_ws, size_t ws_size,
                              hipStream_t stream)
{
    const float* achieved = (const float*)d_in[0];
    const float* desired  = (const float*)d_in[1];
    float* out = (float*)d_out;
    float* rv  = (float*)d_ws;   // 2 KB scratch

    chamfer_bv<<<NB * NV, 512, 0, stream>>>(achieved, desired, rv);
    chamfer_finalize<<<1, 256, 0, stream>>>(rv, out);
}

// Round 4
// 32.041 us; speedup vs baseline: 2.6322x; 1.9921x over previous
//
#include <hip/hip_runtime.h>
#include <math.h>

#define NB 256
#define NV 2
#define NN 512
#define ND 10
#define THRESH_SQ 6.0f
#define EPS_W 1e-6f

typedef __attribute__((ext_vector_type(8))) short bf16x8;
typedef __attribute__((ext_vector_type(4))) float f32x4;

__device__ __forceinline__ unsigned short f2bf(float x) {
    union { float f; unsigned u; } v; v.f = x;
    unsigned r = v.u + 0x7FFFu + ((v.u >> 16) & 1u);   // RNE
    return (unsigned short)(r >> 16);
}
__device__ __forceinline__ float bf2f(unsigned short h) {
    union { unsigned u; float f; } v; v.u = ((unsigned)h) << 16; return v.f;
}
__device__ __forceinline__ void split3(float x, unsigned short* s) {
    unsigned short h = f2bf(x); float r = x - bf2f(h);
    unsigned short m = f2bf(r); float r2 = r - bf2f(m);
    s[0] = h; s[1] = m; s[2] = f2bf(r2);
}
__device__ __forceinline__ unsigned umin_(unsigned a, unsigned b) { return a < b ? a : b; }

// chunk-major record layout, XOR-swizzled; byte offset within the 32KB buffer
__device__ __forceinline__ int recaddr(int c, int row) {
    return (c << 13) + ((row << 4) ^ (c << 5));
}

// One block (512 thr) per bv. P (+2^-10 bias) via bf16-split MFMA; both argmin
// axes tracked as packed u32 keys (value-high-bits | index), col-axis merged
// through LDS atomicMin. Epilogue formulas identical to round 1/3 (absmax 0).
__global__ __launch_bounds__(512, 6)
void chamfer_bv(const float* __restrict__ achieved,
                const float* __restrict__ desired,
                float* __restrict__ rv_out)
{
    const int bv  = blockIdx.x;
    const int tid = threadIdx.x;

    __shared__ __align__(16) char buf[32768];     // A records, then B records
    __shared__ unsigned colKey[NN];
    __shared__ unsigned rowKeyArr[NN];
    __shared__ int cnt[NN];                        // A counts low16, B counts high16
    __shared__ float redF[16];
    __shared__ int   redI[16];

    const float* arow = achieved + ((size_t)bv * NN + tid) * ND;
    const float* drow = desired  + ((size_t)bv * NN + tid) * ND;

    const unsigned short ONE = 0x3F80;
    const int pi[6] = {0,0,1,2,1,0};   // split-product pairs with i+j<=2
    const int pj[6] = {0,1,0,0,1,2};

    const float g5 = drow[5], g6 = drow[6], g7 = drow[7], g8 = drow[8];

    // ---- phase 1: A records (achieved; -2-scaled splits + sn2 + ONEs) ----
    {
        float a5 = arow[5], a6 = arow[6], a7 = arow[7], a8 = arow[8];
        unsigned short us[4][3];
        split3(-2.0f*a5, us[0]); split3(-2.0f*a6, us[1]);
        split3(-2.0f*a7, us[2]); split3(-2.0f*a8, us[3]);
        float sn2 = a5*a5 + a6*a6 + a7*a7 + a8*a8;
        unsigned short sn[3]; split3(sn2, sn);
        unsigned short t[32];
        #pragma unroll
        for (int d = 0; d < 4; ++d)
            #pragma unroll
            for (int p = 0; p < 6; ++p)
                t[d*6+p] = us[d][pi[p]];
        t[24]=sn[0]; t[25]=sn[1]; t[26]=sn[2];
        t[27]=ONE;   t[28]=ONE;   t[29]=ONE;
        t[30]=ONE;   t[31]=0;                       // pairs with bias in B
        #pragma unroll
        for (int c = 0; c < 4; ++c) {
            bf16x8 v;
            #pragma unroll
            for (int e = 0; e < 8; ++e) v[e] = (short)t[c*8+e];
            *(bf16x8*)(buf + recaddr(c, tid)) = v;
        }
    }
    colKey[tid] = 0xFFFFFFFFu;
    cnt[tid] = 0;
    __syncthreads();

    const int lane = tid & 63, wid = tid >> 6;
    const int lrow = lane & 15, lchk = lane >> 4;

    bf16x8 afr[4];
    #pragma unroll
    for (int nt = 0; nt < 4; ++nt)
        afr[nt] = *(const bf16x8*)(buf + recaddr(lchk, (wid<<6) + (nt<<4) + lrow));
    __syncthreads();   // A region dead

    // ---- phase 2: B records (desired) overwrite the same buffer ----
    {
        unsigned short gs[4][3];
        split3(g5, gs[0]); split3(g6, gs[1]); split3(g7, gs[2]); split3(g8, gs[3]);
        float gn2 = g5*g5 + g6*g6 + g7*g7 + g8*g8;
        unsigned short gn[3]; split3(gn2, gn);
        unsigned short t[32];
        #pragma unroll
        for (int d = 0; d < 4; ++d)
            #pragma unroll
            for (int p = 0; p < 6; ++p)
                t[d*6+p] = gs[d][pj[p]];
        t[24]=ONE;   t[25]=ONE;   t[26]=ONE;
        t[27]=gn[0]; t[28]=gn[1]; t[29]=gn[2];
        t[30]=0x3A80; t[31]=0;                      // +2^-10 bias -> P strictly > 0
        #pragma unroll
        for (int c = 0; c < 4; ++c) {
            bf16x8 v;
            #pragma unroll
            for (int e = 0; e < 8; ++e) v[e] = (short)t[c*8+e];
            *(bf16x8*)(buf + recaddr(c, tid)) = v;
        }
    }
    __syncthreads();

    unsigned rowKey[4][4];
    int ncst[4][4];
    #pragma unroll
    for (int nt = 0; nt < 4; ++nt)
        #pragma unroll
        for (int j = 0; j < 4; ++j) {
            rowKey[nt][j] = 0xFFFFFFFFu;
            ncst[nt][j]   = (wid<<6) + (nt<<4) + (lchk<<2) + j;
        }

    const unsigned MASK = 0xFFFFFE00u;
    const f32x4 z = {0.0f, 0.0f, 0.0f, 0.0f};

    // ---- main loop: 32 m-tiles; 4 VALU/elem argmin via packed keys ----
    #pragma unroll 4
    for (int mt = 0; mt < 32; ++mt) {
        bf16x8 bfr = *(const bf16x8*)(buf + recaddr(lchk, (mt<<4) + lrow));
        const unsigned mcur = (unsigned)((mt<<4) + lrow);
        unsigned cv = 0xFFFFFFFFu;
        #pragma unroll
        for (int nt = 0; nt < 4; ++nt) {
            f32x4 acc = __builtin_amdgcn_mfma_f32_16x16x32_bf16(afr[nt], bfr, z, 0, 0, 0);
            #pragma unroll
            for (int j = 0; j < 4; ++j) {
                unsigned bits = __float_as_uint(acc[j]);
                unsigned kr = (bits & MASK) | mcur;                    // row key (idx=m)
                unsigned kc = (bits & MASK) | (unsigned)ncst[nt][j];   // col key (idx=n)
                rowKey[nt][j] = umin_(rowKey[nt][j], kr);
                cv = umin_(cv, kc);
            }
        }
        atomicMin(&colKey[mcur], cv);   // 4-way aliased, fire-and-forget
    }

    // ---- row combine across the 16 lrow lanes (same n per slot) ----
    #pragma unroll
    for (int nt = 0; nt < 4; ++nt) {
        #pragma unroll
        for (int j = 0; j < 4; ++j) {
            unsigned v = rowKey[nt][j];
            #pragma unroll
            for (int s = 1; s <= 8; s <<= 1)
                v = umin_(v, (unsigned)__shfl_xor((int)v, s));
            if (lrow == 0) rowKeyArr[ncst[nt][j]] = v;
        }
    }
    __syncthreads();

    // ---- epilogue: thread tid owns goal m=tid (dir A) and state n=tid (dir B) ----
    const unsigned kA = colKey[tid];
    const unsigned kB = rowKeyArr[tid];
    const int miA = (int)(kA & 0x1FFu);
    const int miB = (int)(kB & 0x1FFu);
    const bool latA = __uint_as_float(kA & MASK) > THRESH_SQ;
    const bool latB = __uint_as_float(kB & MASK) > THRESH_SQ;
    if (!latA) atomicAdd(&cnt[miA], 1);
    if (!latB) atomicAdd(&cnt[miB], 0x10000);
    __syncthreads();

    float sumA = 0.0f, sumB = 0.0f;
    if (!latA) {
        const float* sp = achieved + ((size_t)bv * NN + miA) * ND;
        float dx = drow[0] - sp[0], dy = drow[1] - sp[1];
        float w = 1.0f / ((float)(cnt[miA] & 0xFFFF) + EPS_W);
        sumA = w * sqrtf(dx*dx + dy*dy);
    }
    if (!latB) {
        const float* gp = desired + ((size_t)bv * NN + miB) * ND;
        float dx = arow[0] - gp[0], dy = arow[1] - gp[1];
        float w = 1.0f / ((float)(((unsigned)cnt[miB]) >> 16) + EPS_W);
        sumB = w * sqrtf(dx*dx + dy*dy);
    }
    const int c0 = cnt[tid];
    int grpPk = ((c0 & 0xFFFF) ? 1 : 0) | ((((unsigned)c0) >> 16) ? 0x10000 : 0);
    int latPk = (latA ? 1 : 0) | (latB ? 2 : 0);

    #pragma unroll
    for (int off = 32; off > 0; off >>= 1) {
        sumA  += __shfl_down(sumA, off);
        sumB  += __shfl_down(sumB, off);
        grpPk += __shfl_down(grpPk, off);
        latPk |= __shfl_down(latPk, off);
    }
    if (lane == 0) {
        redF[wid*2] = sumA; redF[wid*2+1] = sumB;
        redI[wid*2] = grpPk; redI[wid*2+1] = latPk;
    }
    __syncthreads();
    if (tid == 0) {
        float sA = 0.0f, sB = 0.0f; int G = 0, L = 0;
        #pragma unroll
        for (int w2 = 0; w2 < 8; ++w2) {
            sA += redF[w2*2]; sB += redF[w2*2+1];
            G  += redI[w2*2]; L |= redI[w2*2+1];
        }
        float unmA = (L & 1) ? 1.0f : 0.0f;
        float unmB = (L & 2) ? 1.0f : 0.0f;
        float gA = (float)(G & 0xFFFF), gB = (float)(((unsigned)G) >> 16);
        float rA = -(sA + unmA) / fmaxf(gA + unmA, 1.0f);
        float rB = -(sB + unmB) / fmaxf(gB + unmB, 1.0f);
        rv_out[bv] = 0.5f * (rA + rB);
    }
}

// out[b] = mean over v
__global__ void chamfer_finalize(const float* __restrict__ rv, float* __restrict__ out)
{
    int b = blockIdx.x * 256 + threadIdx.x;
    if (b < NB) out[b] = 0.5f * (rv[2*b] + rv[2*b + 1]);
}

extern "C" void kernel_launch(void* const* d_in, const int* in_sizes, int n_in,
                              void* d_out, int out_size, void* d_ws, size_t ws_size,
                              hipStream_t stream)
{
    const float* achieved = (const float*)d_in[0];
    const float* desired  = (const float*)d_in[1];
    float* out = (float*)d_out;
    float* rv  = (float*)d_ws;   // 2 KB scratch

    chamfer_bv<<<NB * NV, 512, 0, stream>>>(achieved, desired, rv);
    chamfer_finalize<<<1, 256, 0, stream>>>(rv, out);
}